// Round 6
// baseline (226.450 us; speedup 1.0000x reference)
//
#include <hip/hip_runtime.h>

typedef _Float16 f16;
typedef f16 f16x4 __attribute__((ext_vector_type(4)));
typedef f16 f16x8 __attribute__((ext_vector_type(8)));
typedef float f32x4 __attribute__((ext_vector_type(4)));

#define AS1 __attribute__((address_space(1)))
#define AS3 __attribute__((address_space(3)))

constexpr float kScale  = 7.896444077714954f;                       // 6 * 3^0.25
// q scale: SCALE / sqrt(512) * log2(e)  (scores produced directly in log2 units)
constexpr float kScaleQ = (float)(7.896444077714954 / 22.627416997969522 * 1.4426950408889634);

__device__ __forceinline__ void g2l16(const void* g, void* l) {
  __builtin_amdgcn_global_load_lds((const AS1 void*)g, (AS3 void*)l, 16, 0, 0);
}

// ---------------- LayerNorm: fp32 [rows,512] -> f16 ----------------
__global__ __launch_bounds__(256) void ln_kernel(
    const float* __restrict__ x, const float* __restrict__ g,
    const float* __restrict__ be, f16* __restrict__ out) {
  int row = blockIdx.x * 4 + (threadIdx.x >> 6);
  int lane = threadIdx.x & 63;
  const float* xr = x + (size_t)row * 512;
  float xa[8];
  *(float4*)&xa[0] = *(const float4*)(xr + lane * 8);
  *(float4*)&xa[4] = *(const float4*)(xr + lane * 8 + 4);
  float s = 0.f, q = 0.f;
#pragma unroll
  for (int i = 0; i < 8; ++i) { s += xa[i]; q += xa[i] * xa[i]; }
#pragma unroll
  for (int off = 32; off; off >>= 1) { s += __shfl_xor(s, off); q += __shfl_xor(q, off); }
  float mean = s * (1.f / 512.f);
  float var = q * (1.f / 512.f) - mean * mean;
  float rstd = rsqrtf(var + 1e-5f);
  float ga[8], ba[8];
  *(float4*)&ga[0] = *(const float4*)(g + lane * 8);
  *(float4*)&ga[4] = *(const float4*)(g + lane * 8 + 4);
  *(float4*)&ba[0] = *(const float4*)(be + lane * 8);
  *(float4*)&ba[4] = *(const float4*)(be + lane * 8 + 4);
  f16x8 o;
#pragma unroll
  for (int i = 0; i < 8; ++i) o[i] = (f16)((xa[i] - mean) * rstd * ga[i] + ba[i]);
  *(f16x8*)(out + (size_t)row * 512 + lane * 8) = o;
}

// ------------- transpose + f16 convert: out[Cc][R] = in[R][Cc]*scale -------------
__global__ __launch_bounds__(256) void transpose_cvt(
    const float* __restrict__ in, f16* __restrict__ out,
    int R, int Cc, long ibs, long obs, float scale) {
  __shared__ float t[32][33];
  int b = blockIdx.z;
  const float* im = in + (size_t)b * ibs;
  int c0 = blockIdx.x * 32, r0 = blockIdx.y * 32;
  int tx = threadIdx.x & 31, ty = threadIdx.x >> 5;
#pragma unroll
  for (int i = 0; i < 4; ++i) {
    int rr = ty + i * 8;
    t[rr][tx] = im[(size_t)(r0 + rr) * Cc + c0 + tx] * scale;
  }
  __syncthreads();
#pragma unroll
  for (int i = 0; i < 4; ++i) {
    int rr = ty + i * 8;
    out[(size_t)b * obs + (size_t)(c0 + rr) * R + r0 + tx] = (f16)t[tx][rr];
  }
}

// ------------- GEMM: C[M,N] = A[M,K] * Bt[N,K]^T, f16 in, fp32 acc -------------
// MODE 0: qkv scatter (q,k -> [B,H,T,64]; v -> [B,H,D,T])
// MODE 1: out fp32 = acc + bias + res
// MODE 2: out f16  = relu(acc + bias)
// MODE 3: out fp32 = acc + bias*kScale + res
template <int MODE>
__global__ __launch_bounds__(256) void gemm_bt(
    const f16* __restrict__ A, const f16* __restrict__ Bt,
    const float* __restrict__ bias, const float* __restrict__ res,
    float* __restrict__ outf, f16* __restrict__ outb,
    f16* __restrict__ qo, f16* __restrict__ ko, f16* __restrict__ vo,
    int N, int K) {
  __shared__ f16 lA[128 * 64], lB[128 * 64];
  int tid = threadIdx.x;
  int lane = tid & 63, w = tid >> 6;
  int wr = w >> 1, wc = w & 1, gq = lane >> 4, r = lane & 15;
  int m0 = blockIdx.x * 128, n0 = blockIdx.y * 128;
  size_t Kb = (size_t)K * 2;
  const char* Ab = (const char*)A + (size_t)m0 * Kb;
  const char* Bb = (const char*)Bt + (size_t)n0 * Kb;
  f32x4 acc[4][4] = {};
  int srow = lane >> 3, sslot = lane & 7;
  for (int kt = 0; kt < K; kt += 64) {
#pragma unroll
    for (int i = 0; i < 4; ++i) {
      int chunk = i * 4 + w;
      int row = chunk * 8 + srow;
      int slot = sslot ^ (row & 7);
      g2l16(Ab + (size_t)row * Kb + kt * 2 + slot * 16, (char*)lA + chunk * 1024);
      g2l16(Bb + (size_t)row * Kb + kt * 2 + slot * 16, (char*)lB + chunk * 1024);
    }
    __syncthreads();
    f16x8 af[4][2], bfr[4][2];
#pragma unroll
    for (int f = 0; f < 4; ++f)
#pragma unroll
      for (int ks = 0; ks < 2; ++ks) {
        int ra = wr * 64 + f * 16 + r;
        af[f][ks] = *(const f16x8*)((const char*)lA + ra * 128 + (((ks * 4 + gq) ^ (ra & 7)) * 16));
        int rb = wc * 64 + f * 16 + r;
        bfr[f][ks] = *(const f16x8*)((const char*)lB + rb * 128 + (((ks * 4 + gq) ^ (rb & 7)) * 16));
      }
#pragma unroll
    for (int fm = 0; fm < 4; ++fm)
#pragma unroll
      for (int fn = 0; fn < 4; ++fn)
#pragma unroll
        for (int ks = 0; ks < 2; ++ks)
          acc[fm][fn] = __builtin_amdgcn_mfma_f32_16x16x32_f16(af[fm][ks], bfr[fn][ks], acc[fm][fn], 0, 0, 0);
    __syncthreads();
  }
#pragma unroll
  for (int fm = 0; fm < 4; ++fm)
#pragma unroll
    for (int fn = 0; fn < 4; ++fn)
#pragma unroll
      for (int rg = 0; rg < 4; ++rg) {
        int row = m0 + wr * 64 + fm * 16 + gq * 4 + rg;
        int col = n0 + wc * 64 + fn * 16 + r;
        float v = acc[fm][fn][rg];
        if constexpr (MODE == 1) {
          outf[(size_t)row * N + col] = v + bias[col] + res[(size_t)row * N + col];
        } else if constexpr (MODE == 2) {
          outb[(size_t)row * N + col] = (f16)fmaxf(v + bias[col], 0.f);
        } else if constexpr (MODE == 3) {
          outf[(size_t)row * N + col] = v + bias[col] * kScale + res[(size_t)row * N + col];
        } else {
          int bb = row >> 11, t = row & 2047;
          int which = col >> 9, hd = col & 511, hh = hd >> 6, d = hd & 63;
          size_t bh = (size_t)bb * 8 + hh;
          if (which == 0)      qo[(bh * 2048 + t) * 64 + d] = (f16)v;
          else if (which == 1) ko[(bh * 2048 + t) * 64 + d] = (f16)v;
          else                 vo[(bh * 64 + d) * 2048 + t] = (f16)v;
        }
      }
}

// ------------- causal flash attention, paired q-tiles + split-KV -------------
// q,k:[B,H,T,64], v^T:[B,H,64,T]. Block (bh, p, half) handles q-tiles A=p and
// B=31-p over kv tiles with kv % 2 == half. Scores arrive in log2 units
// (log2e folded into q); softmax uses exp2. Unnormalized partials (O,m,l) to ws.
__global__ __launch_bounds__(256) void attn_kernel(
    const f16* __restrict__ Q, const f16* __restrict__ K,
    const f16* __restrict__ Vt, float* __restrict__ Opart,
    float* __restrict__ mpart, float* __restrict__ lpart) {
  __shared__ f16 lK[64 * 64], lV[64 * 64];
  __shared__ f16 lP[4][16 * 72];
  int tid = threadIdx.x, lane = tid & 63, w = tid >> 6;
  int gq = lane >> 4, r = lane & 15;
  int bh = blockIdx.x;     // 0..31
  int p = blockIdx.y;      // 0..15 -> tiles p and 31-p
  int half = blockIdx.z;   // 0/1: kv parity
  const char* Qb = (const char*)(Q + (size_t)bh * 2048 * 64);
  const char* Kb = (const char*)(K + (size_t)bh * 2048 * 64);
  const char* Vb = (const char*)(Vt + (size_t)bh * 64 * 2048);
  int q0A = p * 64 + w * 16;
  int q0B = (31 - p) * 64 + w * 16;
  f16x8 qfA[2], qfB[2];
#pragma unroll
  for (int ks = 0; ks < 2; ++ks) {
    qfA[ks] = *(const f16x8*)(Qb + (size_t)(q0A + r) * 128 + ks * 64 + gq * 16);
    qfB[ks] = *(const f16x8*)(Qb + (size_t)(q0B + r) * 128 + ks * 64 + gq * 16);
  }
  f32x4 OA[4] = {}, OB[4] = {};
  float mA[4], lA_[4], mB[4], lB_[4];
#pragma unroll
  for (int rg = 0; rg < 4; ++rg) { mA[rg] = mB[rg] = -1e30f; lA_[rg] = lB_[rg] = 0.f; }
  int srow = lane >> 3, sslot = lane & 7;

  f16x8 vf[4][2];
  auto smpv = [&](f32x4 (&s)[4], float (&m)[4], float (&l)[4], f32x4 (&O)[4]) {
#pragma unroll
    for (int rg = 0; rg < 4; ++rg) {
      float v = fmaxf(fmaxf(s[0][rg], s[1][rg]), fmaxf(s[2][rg], s[3][rg]));
      v = fmaxf(v, __shfl_xor(v, 1));
      v = fmaxf(v, __shfl_xor(v, 2));
      v = fmaxf(v, __shfl_xor(v, 4));
      v = fmaxf(v, __shfl_xor(v, 8));
      float mo = m[rg];
      float mn = fmaxf(mo, v);
      if (mn - mo > 11.5f) {  // defer-max (log2 units)
        float sc = exp2f(mo - mn);
        l[rg] *= sc;
#pragma unroll
        for (int fd = 0; fd < 4; ++fd) O[fd][rg] *= sc;
        m[rg] = mn;
      } else {
        mn = mo;
      }
      float ps = 0.f;
      int prow = gq * 4 + rg;
#pragma unroll
      for (int fc = 0; fc < 4; ++fc) {
        float pe = exp2f(s[fc][rg] - mn);
        ps += pe;
        lP[w][prow * 72 + fc * 16 + r] = (f16)pe;
      }
      ps += __shfl_xor(ps, 1);
      ps += __shfl_xor(ps, 2);
      ps += __shfl_xor(ps, 4);
      ps += __shfl_xor(ps, 8);
      l[rg] += ps;
    }
    f16x8 pf[2];
#pragma unroll
    for (int ks = 0; ks < 2; ++ks)
      pf[ks] = *(const f16x8*)((const char*)&lP[w][0] + r * 144 + ks * 64 + gq * 16);
#pragma unroll
    for (int fd = 0; fd < 4; ++fd)
#pragma unroll
      for (int ks = 0; ks < 2; ++ks)
        O[fd] = __builtin_amdgcn_mfma_f32_16x16x32_f16(pf[ks], vf[fd][ks], O[fd], 0, 0, 0);
  };

  int nkv = 32 - p;
  for (int kv = half; kv < nkv; kv += 2) {
    int j0 = kv * 64;
#pragma unroll
    for (int i = 0; i < 2; ++i) {
      int chunk = i * 4 + w;
      int row = chunk * 8 + srow;
      int slot = sslot ^ (row & 7);
      g2l16(Kb + (size_t)(j0 + row) * 128 + slot * 16, (char*)lK + chunk * 1024);
      g2l16(Vb + (size_t)row * 4096 + j0 * 2 + slot * 16, (char*)lV + chunk * 1024);
    }
    __syncthreads();
    f16x8 kf[4][2];
#pragma unroll
    for (int fc = 0; fc < 4; ++fc)
#pragma unroll
      for (int ks = 0; ks < 2; ++ks) {
        int rj = fc * 16 + r;
        kf[fc][ks] = *(const f16x8*)((const char*)lK + rj * 128 + (((ks * 4 + gq) ^ (rj & 7)) * 16));
      }
#pragma unroll
    for (int fd = 0; fd < 4; ++fd)
#pragma unroll
      for (int ks = 0; ks < 2; ++ks) {
        int rd = fd * 16 + r;
        vf[fd][ks] = *(const f16x8*)((const char*)lV + rd * 128 + (((ks * 4 + gq) ^ (rd & 7)) * 16));
      }
    f32x4 sB[4] = {};
#pragma unroll
    for (int ks = 0; ks < 2; ++ks)
#pragma unroll
      for (int fc = 0; fc < 4; ++fc)
        sB[fc] = __builtin_amdgcn_mfma_f32_16x16x32_f16(qfB[ks], kf[fc][ks], sB[fc], 0, 0, 0);
    if (kv == nkv - 1) {  // diagonal tile for B
#pragma unroll
      for (int fc = 0; fc < 4; ++fc)
#pragma unroll
        for (int rg = 0; rg < 4; ++rg) {
          int t = q0B + gq * 4 + rg;
          int j = j0 + fc * 16 + r;
          if (j > t) sB[fc][rg] = -1e30f;
        }
    }
    smpv(sB, mB, lB_, OB);
    if (kv <= p) {
      f32x4 sA[4] = {};
#pragma unroll
      for (int ks = 0; ks < 2; ++ks)
#pragma unroll
        for (int fc = 0; fc < 4; ++fc)
          sA[fc] = __builtin_amdgcn_mfma_f32_16x16x32_f16(qfA[ks], kf[fc][ks], sA[fc], 0, 0, 0);
      if (kv == p) {  // diagonal tile for A
#pragma unroll
        for (int fc = 0; fc < 4; ++fc)
#pragma unroll
          for (int rg = 0; rg < 4; ++rg) {
            int t = q0A + gq * 4 + rg;
            int j = j0 + fc * 16 + r;
            if (j > t) sA[fc][rg] = -1e30f;
          }
      }
      smpv(sA, mA, lA_, OA);
    }
    __syncthreads();
  }
  // write unnormalized partials (every (tile,half) slice written exactly once)
  auto wpart = [&](int tile, f32x4 (&O)[4], float (&m)[4], float (&l)[4]) {
    size_t ib = ((size_t)bh * 32 + tile) * 2 + half;
    float* Ob = Opart + ib * 4096;
    int rowb = w * 16 + gq * 4;
#pragma unroll
    for (int fd = 0; fd < 4; ++fd)
#pragma unroll
      for (int rg = 0; rg < 4; ++rg)
        Ob[(size_t)(rowb + rg) * 64 + fd * 16 + r] = O[fd][rg];
    if (r == 0) {
#pragma unroll
      for (int rg = 0; rg < 4; ++rg) {
        mpart[ib * 64 + rowb + rg] = m[rg];
        lpart[ib * 64 + rowb + rg] = l[rg];
      }
    }
  };
  wpart(p, OA, mA, lA_);
  wpart(31 - p, OB, mB, lB_);
}

// ------------- combine the two split-KV halves -> f16 attn output -------------
__global__ __launch_bounds__(256) void attn_combine(
    const float* __restrict__ Opart, const float* __restrict__ mpart,
    const float* __restrict__ lpart, f16* __restrict__ out) {
  int bh = blockIdx.x, tile = blockIdx.y;
  int tid = threadIdx.x;
  int row = tid >> 2, cg = tid & 3;
  size_t i0 = ((size_t)bh * 32 + tile) * 2;
  size_t i1 = i0 + 1;
  float m1 = mpart[i0 * 64 + row], m2 = mpart[i1 * 64 + row];
  float l1 = lpart[i0 * 64 + row], l2 = lpart[i1 * 64 + row];
  float m = fmaxf(m1, m2);
  float w1 = exp2f(m1 - m), w2 = exp2f(m2 - m);
  float inv = 1.f / (l1 * w1 + l2 * w2);
  w1 *= inv; w2 *= inv;
  int bb = bh >> 3, hh = bh & 7;
  int t = tile * 64 + row;
  const float* O1 = Opart + i0 * 4096 + (size_t)row * 64 + cg * 16;
  const float* O2 = Opart + i1 * 4096 + (size_t)row * 64 + cg * 16;
  f16* o = out + ((size_t)bb * 2048 + t) * 512 + hh * 64 + cg * 16;
#pragma unroll
  for (int j = 0; j < 16; j += 4) {
    float4 a = *(const float4*)(O1 + j);
    float4 b = *(const float4*)(O2 + j);
    f16x4 v;
    v[0] = (f16)(a.x * w1 + b.x * w2);
    v[1] = (f16)(a.y * w1 + b.y * w2);
    v[2] = (f16)(a.z * w1 + b.z * w2);
    v[3] = (f16)(a.w * w1 + b.w * w2);
    *(f16x4*)(o + j) = v;
  }
}

extern "C" void kernel_launch(void* const* d_in, const int* in_sizes, int n_in,
                              void* d_out, int out_size, void* d_ws, size_t ws_size,
                              hipStream_t stream) {
  (void)in_sizes; (void)n_in; (void)out_size; (void)ws_size;
  const float* x      = (const float*)d_in[0];
  const float* wq     = (const float*)d_in[1];
  const float* wk     = (const float*)d_in[2];
  const float* wv     = (const float*)d_in[3];
  const float* w_proj = (const float*)d_in[4];
  const float* b_proj = (const float*)d_in[5];
  const float* w1     = (const float*)d_in[6];
  const float* b1     = (const float*)d_in[7];
  const float* w2     = (const float*)d_in[8];
  const float* b2     = (const float*)d_in[9];
  const float* g1     = (const float*)d_in[10];
  const float* be1    = (const float*)d_in[11];
  const float* g2     = (const float*)d_in[12];
  const float* be2    = (const float*)d_in[13];
  float* outp = (float*)d_out;

  char* ws = (char*)d_ws;
  size_t off = 0;
  auto alloc = [&](size_t bytes) {
    char* p = ws + off;
    off += (bytes + 255) & ~(size_t)255;
    return p;
  };
  const size_t MC2 = (size_t)8192 * 512 * 2;   // 8.4 MB
  f16* x_ln  = (f16*)alloc(MC2);
  f16* qb    = (f16*)alloc(MC2);   // qb..attn (33.6 MB) reused as hbuf later
  f16* kb    = (f16*)alloc(MC2);
  f16* vb    = (f16*)alloc(MC2);
  f16* attn  = (f16*)alloc(MC2);
  float* x1  = (float*)alloc((size_t)8192 * 512 * 4);
  f16* Wqkv  = (f16*)alloc((size_t)1536 * 512 * 2);
  f16* Wp    = (f16*)alloc((size_t)512 * 512 * 2);
  f16* W1t   = (f16*)alloc((size_t)2048 * 512 * 2);
  f16* W2t   = (f16*)alloc((size_t)512 * 2048 * 2);
  float* Opart = (float*)alloc((size_t)32 * 32 * 2 * 4096 * 4);  // 33.6 MB
  float* mpart = (float*)alloc((size_t)32 * 32 * 2 * 64 * 4);
  float* lpart = (float*)alloc((size_t)32 * 32 * 2 * 64 * 4);
  f16* x1_ln = x_ln;
  f16* hbuf  = qb;  // 32 MB spans qb..attn

  // weights -> f16, transposed to [N][K]; scales folded (q gets 512^-0.5 * log2e)
  transpose_cvt<<<dim3(2, 16, 8), 256, 0, stream>>>(wq, Wqkv,                 512, 64, 512 * 64, 64 * 512, kScaleQ);
  transpose_cvt<<<dim3(2, 16, 8), 256, 0, stream>>>(wk, Wqkv + 512 * 512,     512, 64, 512 * 64, 64 * 512, kScale);
  transpose_cvt<<<dim3(2, 16, 8), 256, 0, stream>>>(wv, Wqkv + 2 * 512 * 512, 512, 64, 512 * 64, 64 * 512, kScale);
  transpose_cvt<<<dim3(16, 16, 1), 256, 0, stream>>>(w_proj, Wp, 512, 512, 0, 0, 1.f);
  transpose_cvt<<<dim3(64, 16, 1), 256, 0, stream>>>(w1, W1t, 512, 2048, 0, 0, 1.f);
  transpose_cvt<<<dim3(16, 64, 1), 256, 0, stream>>>(w2, W2t, 2048, 512, 0, 0, kScale);

  ln_kernel<<<2048, 256, 0, stream>>>(x, g1, be1, x_ln);
  gemm_bt<0><<<dim3(64, 12), 256, 0, stream>>>(x_ln, Wqkv, nullptr, nullptr, nullptr, nullptr,
                                               qb, kb, vb, 1536, 512);
  attn_kernel<<<dim3(32, 16, 2), 256, 0, stream>>>(qb, kb, vb, Opart, mpart, lpart);
  attn_combine<<<dim3(32, 32), 256, 0, stream>>>(Opart, mpart, lpart, attn);
  gemm_bt<1><<<dim3(64, 4), 256, 0, stream>>>(attn, Wp, b_proj, x, x1, nullptr,
                                              nullptr, nullptr, nullptr, 512, 512);
  ln_kernel<<<2048, 256, 0, stream>>>(x1, g2, be2, x1_ln);
  gemm_bt<2><<<dim3(64, 16), 256, 0, stream>>>(x1_ln, W1t, b1, nullptr, nullptr, hbuf,
                                               nullptr, nullptr, nullptr, 2048, 512);
  gemm_bt<3><<<dim3(64, 4), 256, 0, stream>>>(hbuf, W2t, b2, x1, outp, nullptr,
                                              nullptr, nullptr, nullptr, 512, 2048);
}

// Round 7
// 208.621 us; speedup vs baseline: 1.0855x; 1.0855x over previous
//
#include <hip/hip_runtime.h>

typedef _Float16 f16;
typedef f16 f16x8 __attribute__((ext_vector_type(8)));
typedef float f32x4 __attribute__((ext_vector_type(4)));

#define AS1 __attribute__((address_space(1)))
#define AS3 __attribute__((address_space(3)))

constexpr float kScale  = 7.896444077714954f;                       // 6 * 3^0.25
// q scale: SCALE / sqrt(512) * log2(e)  (scores produced directly in log2 units)
constexpr float kScaleQ = (float)(7.896444077714954 / 22.627416997969522 * 1.4426950408889634);

__device__ __forceinline__ void g2l16(const void* g, void* l) {
  __builtin_amdgcn_global_load_lds((const AS1 void*)g, (AS3 void*)l, 16, 0, 0);
}

// ---------------- LayerNorm: fp32 [rows,512] -> f16 ----------------
__global__ __launch_bounds__(256) void ln_kernel(
    const float* __restrict__ x, const float* __restrict__ g,
    const float* __restrict__ be, f16* __restrict__ out) {
  int row = blockIdx.x * 4 + (threadIdx.x >> 6);
  int lane = threadIdx.x & 63;
  const float* xr = x + (size_t)row * 512;
  float xa[8];
  *(float4*)&xa[0] = *(const float4*)(xr + lane * 8);
  *(float4*)&xa[4] = *(const float4*)(xr + lane * 8 + 4);
  float s = 0.f, q = 0.f;
#pragma unroll
  for (int i = 0; i < 8; ++i) { s += xa[i]; q += xa[i] * xa[i]; }
#pragma unroll
  for (int off = 32; off; off >>= 1) { s += __shfl_xor(s, off); q += __shfl_xor(q, off); }
  float mean = s * (1.f / 512.f);
  float var = q * (1.f / 512.f) - mean * mean;
  float rstd = rsqrtf(var + 1e-5f);
  float ga[8], ba[8];
  *(float4*)&ga[0] = *(const float4*)(g + lane * 8);
  *(float4*)&ga[4] = *(const float4*)(g + lane * 8 + 4);
  *(float4*)&ba[0] = *(const float4*)(be + lane * 8);
  *(float4*)&ba[4] = *(const float4*)(be + lane * 8 + 4);
  f16x8 o;
#pragma unroll
  for (int i = 0; i < 8; ++i) o[i] = (f16)((xa[i] - mean) * rstd * ga[i] + ba[i]);
  *(f16x8*)(out + (size_t)row * 512 + lane * 8) = o;
}

// ------------- transpose + f16 convert: out[Cc][R] = in[R][Cc]*scale -------------
__global__ __launch_bounds__(256) void transpose_cvt(
    const float* __restrict__ in, f16* __restrict__ out,
    int R, int Cc, long ibs, long obs, float scale) {
  __shared__ float t[32][33];
  int b = blockIdx.z;
  const float* im = in + (size_t)b * ibs;
  int c0 = blockIdx.x * 32, r0 = blockIdx.y * 32;
  int tx = threadIdx.x & 31, ty = threadIdx.x >> 5;
#pragma unroll
  for (int i = 0; i < 4; ++i) {
    int rr = ty + i * 8;
    t[rr][tx] = im[(size_t)(r0 + rr) * Cc + c0 + tx] * scale;
  }
  __syncthreads();
#pragma unroll
  for (int i = 0; i < 4; ++i) {
    int rr = ty + i * 8;
    out[(size_t)b * obs + (size_t)(c0 + rr) * R + r0 + tx] = (f16)t[tx][rr];
  }
}

// ------------- GEMM: C[M,N] = A[M,K] * Bt[N,K]^T, f16 in, fp32 acc -------------
// Double-buffered LDS, single barrier per K-step (stage issued AFTER barrier,
// waited at the NEXT barrier -> full compute phase to hide memory latency).
// MODE 0: qkv scatter (q,k -> [B,H,T,64]; v -> [B,H,D,T])
// MODE 1: out fp32 = acc + bias + res
// MODE 2: out f16  = relu(acc + bias)
// MODE 3: out fp32 = acc + bias*kScale + res
template <int MODE>
__global__ __launch_bounds__(256) void gemm_bt(
    const f16* __restrict__ A, const f16* __restrict__ Bt,
    const float* __restrict__ bias, const float* __restrict__ res,
    float* __restrict__ outf, f16* __restrict__ outb,
    f16* __restrict__ qo, f16* __restrict__ ko, f16* __restrict__ vo,
    int N, int K) {
  __shared__ f16 lA[2][128 * 64], lB[2][128 * 64];
  int tid = threadIdx.x;
  int lane = tid & 63, w = tid >> 6;
  int wr = w >> 1, wc = w & 1, gq = lane >> 4, r = lane & 15;
  int m0 = blockIdx.x * 128, n0 = blockIdx.y * 128;
  size_t Kb = (size_t)K * 2;
  const char* Ab = (const char*)A + (size_t)m0 * Kb;
  const char* Bb = (const char*)Bt + (size_t)n0 * Kb;
  f32x4 acc[4][4] = {};
  int srow = lane >> 3, sslot = lane & 7;
  auto stage = [&](int buf, int kt) {
#pragma unroll
    for (int i = 0; i < 4; ++i) {
      int chunk = i * 4 + w;
      int row = chunk * 8 + srow;
      int slot = sslot ^ (row & 7);
      g2l16(Ab + (size_t)row * Kb + kt * 2 + slot * 16, (char*)lA + buf * 16384 + chunk * 1024);
      g2l16(Bb + (size_t)row * Kb + kt * 2 + slot * 16, (char*)lB + buf * 16384 + chunk * 1024);
    }
  };
  stage(0, 0);
  int cur = 0;
  for (int kt = 0; kt < K; kt += 64) {
    __syncthreads();
    if (kt + 64 < K) stage(cur ^ 1, kt + 64);
    const char* bA = (const char*)lA + cur * 16384;
    const char* bB = (const char*)lB + cur * 16384;
    f16x8 af[4][2], bfr[4][2];
#pragma unroll
    for (int f = 0; f < 4; ++f)
#pragma unroll
      for (int ks = 0; ks < 2; ++ks) {
        int ra = wr * 64 + f * 16 + r;
        af[f][ks] = *(const f16x8*)(bA + ra * 128 + (((ks * 4 + gq) ^ (ra & 7)) * 16));
        int rb = wc * 64 + f * 16 + r;
        bfr[f][ks] = *(const f16x8*)(bB + rb * 128 + (((ks * 4 + gq) ^ (rb & 7)) * 16));
      }
    __builtin_amdgcn_s_setprio(1);
#pragma unroll
    for (int fm = 0; fm < 4; ++fm)
#pragma unroll
      for (int fn = 0; fn < 4; ++fn)
#pragma unroll
        for (int ks = 0; ks < 2; ++ks)
          acc[fm][fn] = __builtin_amdgcn_mfma_f32_16x16x32_f16(af[fm][ks], bfr[fn][ks], acc[fm][fn], 0, 0, 0);
    __builtin_amdgcn_s_setprio(0);
    cur ^= 1;
  }
#pragma unroll
  for (int fm = 0; fm < 4; ++fm)
#pragma unroll
    for (int fn = 0; fn < 4; ++fn)
#pragma unroll
      for (int rg = 0; rg < 4; ++rg) {
        int row = m0 + wr * 64 + fm * 16 + gq * 4 + rg;
        int col = n0 + wc * 64 + fn * 16 + r;
        float v = acc[fm][fn][rg];
        if constexpr (MODE == 1) {
          outf[(size_t)row * N + col] = v + bias[col] + res[(size_t)row * N + col];
        } else if constexpr (MODE == 2) {
          outb[(size_t)row * N + col] = (f16)fmaxf(v + bias[col], 0.f);
        } else if constexpr (MODE == 3) {
          outf[(size_t)row * N + col] = v + bias[col] * kScale + res[(size_t)row * N + col];
        } else {
          int bb = row >> 11, t = row & 2047;
          int which = col >> 9, hd = col & 511, hh = hd >> 6, d = hd & 63;
          size_t bh = (size_t)bb * 8 + hh;
          if (which == 0)      qo[(bh * 2048 + t) * 64 + d] = (f16)v;
          else if (which == 1) ko[(bh * 2048 + t) * 64 + d] = (f16)v;
          else                 vo[(bh * 64 + d) * 2048 + t] = (f16)v;
        }
      }
}

// ------------- causal flash attention, paired q-tiles, double-buffered K/V -------------
// q,k:[B,H,T,64], v^T:[B,H,64,T]. Block (bh, p) handles q-tiles A=p and B=31-p
// (64 rows each; 4 waves x 16 rows per tile); every block does exactly 33 tile-iters.
// Scores in log2 units (log2e folded into q); softmax uses exp2.
// Single barrier per KV-iter; next tile's global_load_lds issued right after it.
__global__ __launch_bounds__(256) void attn_kernel(
    const f16* __restrict__ Q, const f16* __restrict__ K,
    const f16* __restrict__ Vt, f16* __restrict__ out) {
  __shared__ f16 lK[2][64 * 64], lV[2][64 * 64];
  __shared__ f16 lP[4][16 * 72];
  int tid = threadIdx.x, lane = tid & 63, w = tid >> 6;
  int gq = lane >> 4, r = lane & 15;
  int bh = blockIdx.x;   // 0..31
  int p = blockIdx.y;    // 0..15 -> tiles p and 31-p
  const char* Qb = (const char*)(Q + (size_t)bh * 2048 * 64);
  const char* Kb = (const char*)(K + (size_t)bh * 2048 * 64);
  const char* Vb = (const char*)(Vt + (size_t)bh * 64 * 2048);
  int q0A = p * 64 + w * 16;
  int q0B = (31 - p) * 64 + w * 16;
  f16x8 qfA[2], qfB[2];
#pragma unroll
  for (int ks = 0; ks < 2; ++ks) {
    qfA[ks] = *(const f16x8*)(Qb + (size_t)(q0A + r) * 128 + ks * 64 + gq * 16);
    qfB[ks] = *(const f16x8*)(Qb + (size_t)(q0B + r) * 128 + ks * 64 + gq * 16);
  }
  f32x4 OA[4] = {}, OB[4] = {};
  float mA[4], lA_[4], mB[4], lB_[4];
#pragma unroll
  for (int rg = 0; rg < 4; ++rg) { mA[rg] = mB[rg] = -1e30f; lA_[rg] = lB_[rg] = 0.f; }
  int srow = lane >> 3, sslot = lane & 7;

  auto stage = [&](int buf, int kv) {
    int j0 = kv * 64;
#pragma unroll
    for (int i = 0; i < 2; ++i) {
      int chunk = i * 4 + w;
      int row = chunk * 8 + srow;
      int slot = sslot ^ (row & 7);
      g2l16(Kb + (size_t)(j0 + row) * 128 + slot * 16, (char*)lK + buf * 8192 + chunk * 1024);
      g2l16(Vb + (size_t)row * 4096 + j0 * 2 + slot * 16, (char*)lV + buf * 8192 + chunk * 1024);
    }
  };

  f16x8 vf[4][2];
  auto smpv = [&](f32x4 (&s)[4], float (&m)[4], float (&l)[4], f32x4 (&O)[4]) {
#pragma unroll
    for (int rg = 0; rg < 4; ++rg) {
      float v = fmaxf(fmaxf(s[0][rg], s[1][rg]), fmaxf(s[2][rg], s[3][rg]));
      v = fmaxf(v, __shfl_xor(v, 1));
      v = fmaxf(v, __shfl_xor(v, 2));
      v = fmaxf(v, __shfl_xor(v, 4));
      v = fmaxf(v, __shfl_xor(v, 8));
      float mo = m[rg];
      float mn = fmaxf(mo, v);
      if (mn - mo > 11.5f) {  // defer-max (log2 units)
        float sc = exp2f(mo - mn);
        l[rg] *= sc;
#pragma unroll
        for (int fd = 0; fd < 4; ++fd) O[fd][rg] *= sc;
        m[rg] = mn;
      } else {
        mn = mo;
      }
      float ps = 0.f;
      int prow = gq * 4 + rg;
#pragma unroll
      for (int fc = 0; fc < 4; ++fc) {
        float pe = exp2f(s[fc][rg] - mn);
        ps += pe;
        lP[w][prow * 72 + fc * 16 + r] = (f16)pe;
      }
      ps += __shfl_xor(ps, 1);
      ps += __shfl_xor(ps, 2);
      ps += __shfl_xor(ps, 4);
      ps += __shfl_xor(ps, 8);
      l[rg] += ps;
    }
    f16x8 pf[2];
#pragma unroll
    for (int ks = 0; ks < 2; ++ks)
      pf[ks] = *(const f16x8*)((const char*)&lP[w][0] + r * 144 + ks * 64 + gq * 16);
    __builtin_amdgcn_s_setprio(1);
#pragma unroll
    for (int fd = 0; fd < 4; ++fd)
#pragma unroll
      for (int ks = 0; ks < 2; ++ks)
        O[fd] = __builtin_amdgcn_mfma_f32_16x16x32_f16(pf[ks], vf[fd][ks], O[fd], 0, 0, 0);
    __builtin_amdgcn_s_setprio(0);
  };

  int nkv = 32 - p;
  stage(0, 0);
  int cur = 0;
  for (int kv = 0; kv < nkv; ++kv) {
    int j0 = kv * 64;
    __syncthreads();
    if (kv + 1 < nkv) stage(cur ^ 1, kv + 1);
    const char* bK = (const char*)lK + cur * 8192;
    const char* bV = (const char*)lV + cur * 8192;
    f16x8 kf[4][2];
#pragma unroll
    for (int fc = 0; fc < 4; ++fc)
#pragma unroll
      for (int ks = 0; ks < 2; ++ks) {
        int rj = fc * 16 + r;
        kf[fc][ks] = *(const f16x8*)(bK + rj * 128 + (((ks * 4 + gq) ^ (rj & 7)) * 16));
      }
#pragma unroll
    for (int fd = 0; fd < 4; ++fd)
#pragma unroll
      for (int ks = 0; ks < 2; ++ks) {
        int rd = fd * 16 + r;
        vf[fd][ks] = *(const f16x8*)(bV + rd * 128 + (((ks * 4 + gq) ^ (rd & 7)) * 16));
      }
    f32x4 sB[4] = {};
    __builtin_amdgcn_s_setprio(1);
#pragma unroll
    for (int ks = 0; ks < 2; ++ks)
#pragma unroll
      for (int fc = 0; fc < 4; ++fc)
        sB[fc] = __builtin_amdgcn_mfma_f32_16x16x32_f16(qfB[ks], kf[fc][ks], sB[fc], 0, 0, 0);
    __builtin_amdgcn_s_setprio(0);
    if (kv == nkv - 1) {  // diagonal tile for B
#pragma unroll
      for (int fc = 0; fc < 4; ++fc)
#pragma unroll
        for (int rg = 0; rg < 4; ++rg) {
          int t = q0B + gq * 4 + rg;
          int j = j0 + fc * 16 + r;
          if (j > t) sB[fc][rg] = -1e30f;
        }
    }
    smpv(sB, mB, lB_, OB);
    if (kv <= p) {
      f32x4 sA[4] = {};
      __builtin_amdgcn_s_setprio(1);
#pragma unroll
      for (int ks = 0; ks < 2; ++ks)
#pragma unroll
        for (int fc = 0; fc < 4; ++fc)
          sA[fc] = __builtin_amdgcn_mfma_f32_16x16x32_f16(qfA[ks], kf[fc][ks], sA[fc], 0, 0, 0);
      __builtin_amdgcn_s_setprio(0);
      if (kv == p) {  // diagonal tile for A
#pragma unroll
        for (int fc = 0; fc < 4; ++fc)
#pragma unroll
          for (int rg = 0; rg < 4; ++rg) {
            int t = q0A + gq * 4 + rg;
            int j = j0 + fc * 16 + r;
            if (j > t) sA[fc][rg] = -1e30f;
          }
      }
      smpv(sA, mA, lA_, OA);
    }
    cur ^= 1;
  }
  int bb = bh >> 3, hh = bh & 7;
#pragma unroll
  for (int fd = 0; fd < 4; ++fd)
#pragma unroll
    for (int rg = 0; rg < 4; ++rg) {
      int d = fd * 16 + r;
      int tA = q0A + gq * 4 + rg;
      int tB = q0B + gq * 4 + rg;
      out[((size_t)bb * 2048 + tA) * 512 + hh * 64 + d] = (f16)(OA[fd][rg] / lA_[rg]);
      out[((size_t)bb * 2048 + tB) * 512 + hh * 64 + d] = (f16)(OB[fd][rg] / lB_[rg]);
    }
}

extern "C" void kernel_launch(void* const* d_in, const int* in_sizes, int n_in,
                              void* d_out, int out_size, void* d_ws, size_t ws_size,
                              hipStream_t stream) {
  (void)in_sizes; (void)n_in; (void)out_size; (void)ws_size;
  const float* x      = (const float*)d_in[0];
  const float* wq     = (const float*)d_in[1];
  const float* wk     = (const float*)d_in[2];
  const float* wv     = (const float*)d_in[3];
  const float* w_proj = (const float*)d_in[4];
  const float* b_proj = (const float*)d_in[5];
  const float* w1     = (const float*)d_in[6];
  const float* b1     = (const float*)d_in[7];
  const float* w2     = (const float*)d_in[8];
  const float* b2     = (const float*)d_in[9];
  const float* g1     = (const float*)d_in[10];
  const float* be1    = (const float*)d_in[11];
  const float* g2     = (const float*)d_in[12];
  const float* be2    = (const float*)d_in[13];
  float* outp = (float*)d_out;

  char* ws = (char*)d_ws;
  size_t off = 0;
  auto alloc = [&](size_t bytes) {
    char* p = ws + off;
    off += (bytes + 255) & ~(size_t)255;
    return p;
  };
  const size_t MC2 = (size_t)8192 * 512 * 2;   // 8.4 MB
  f16* x_ln  = (f16*)alloc(MC2);
  f16* qb    = (f16*)alloc(MC2);   // qb..attn (33.6 MB) reused as hbuf later
  f16* kb    = (f16*)alloc(MC2);
  f16* vb    = (f16*)alloc(MC2);
  f16* attn  = (f16*)alloc(MC2);
  float* x1  = (float*)alloc((size_t)8192 * 512 * 4);
  f16* Wqkv  = (f16*)alloc((size_t)1536 * 512 * 2);
  f16* Wp    = (f16*)alloc((size_t)512 * 512 * 2);
  f16* W1t   = (f16*)alloc((size_t)2048 * 512 * 2);
  f16* W2t   = (f16*)alloc((size_t)512 * 2048 * 2);
  f16* x1_ln = x_ln;
  f16* hbuf  = qb;  // 32 MB spans qb..attn

  // weights -> f16, transposed to [N][K]; scales folded (q gets 512^-0.5 * log2e)
  transpose_cvt<<<dim3(2, 16, 8), 256, 0, stream>>>(wq, Wqkv,                 512, 64, 512 * 64, 64 * 512, kScaleQ);
  transpose_cvt<<<dim3(2, 16, 8), 256, 0, stream>>>(wk, Wqkv + 512 * 512,     512, 64, 512 * 64, 64 * 512, kScale);
  transpose_cvt<<<dim3(2, 16, 8), 256, 0, stream>>>(wv, Wqkv + 2 * 512 * 512, 512, 64, 512 * 64, 64 * 512, kScale);
  transpose_cvt<<<dim3(16, 16, 1), 256, 0, stream>>>(w_proj, Wp, 512, 512, 0, 0, 1.f);
  transpose_cvt<<<dim3(64, 16, 1), 256, 0, stream>>>(w1, W1t, 512, 2048, 0, 0, 1.f);
  transpose_cvt<<<dim3(16, 64, 1), 256, 0, stream>>>(w2, W2t, 2048, 512, 0, 0, kScale);

  ln_kernel<<<2048, 256, 0, stream>>>(x, g1, be1, x_ln);
  gemm_bt<0><<<dim3(64, 12), 256, 0, stream>>>(x_ln, Wqkv, nullptr, nullptr, nullptr, nullptr,
                                               qb, kb, vb, 1536, 512);
  attn_kernel<<<dim3(32, 16), 256, 0, stream>>>(qb, kb, vb, attn);
  gemm_bt<1><<<dim3(64, 4), 256, 0, stream>>>(attn, Wp, b_proj, x, x1, nullptr,
                                              nullptr, nullptr, nullptr, 512, 512);
  ln_kernel<<<2048, 256, 0, stream>>>(x1, g2, be2, x1_ln);
  gemm_bt<2><<<dim3(64, 16), 256, 0, stream>>>(x1_ln, W1t, b1, nullptr, nullptr, hbuf,
                                               nullptr, nullptr, nullptr, 2048, 512);
  gemm_bt<3><<<dim3(64, 4), 256, 0, stream>>>(hbuf, W2t, b2, x1, outp, nullptr,
                                              nullptr, nullptr, nullptr, 512, 2048);
}